// Round 8
// baseline (404.687 us; speedup 1.0000x reference)
//
#include <hip/hip_runtime.h>
#include <math.h>

#define N_ROWS (32 * 64 * 64)   // 131072 rows
#define KCODES 1024
#define DIM 64

typedef __attribute__((ext_vector_type(8))) _Float16 f16x8;
typedef __attribute__((ext_vector_type(16))) float f32x16;
typedef unsigned long long u64;
typedef unsigned int u32;

// d_ws layout:
//   0       double loss_sum
//   8       u32 flag_count
//   16      int counts[1024]            (-> 4112) [zeroed]
//   4352    float bn[1024]              exact chain norms
//   8448    float nbs[1024]             1536 + 128*bn (fp32)
//   16384   char Bh[128K]  fp16 hi codes, fragment-order [tile][s][lc*32+hi*16]
//   147456  char Bl[128K]  fp16 lo codes, same layout
//   278528  u32 flaglist[N_ROWS]
#define WS_FLAGCNT_OFF 8
#define WS_COUNTS_OFF  16
#define WS_BN_OFF      4352
#define WS_NBS_OFF     8448
#define WS_BH_OFF      16384
#define WS_BL_OFF      147456
#define WS_FLIST_OFF   278528
#define WS_ZERO_BYTES  4112

// ---------- prep: exact bn, MFMA C-init consts, fragment-ordered split codes
__global__ void vq_prep(const float* __restrict__ emb,
                        float* __restrict__ bn,
                        float* __restrict__ nbs,
                        char* __restrict__ Bh,
                        char* __restrict__ Bl) {
    int c = blockIdx.x * 256 + threadIdx.x;   // 4 blocks x 256 = 1024 codes
    const float* e = emb + (size_t)c * DIM;
    float s = 0.f;
#pragma unroll
    for (int d = 0; d < DIM; ++d) s = fmaf(e[d], e[d], s);
    bn[c] = s;
    nbs[c] = fmaf(s, 128.0f, 1536.0f);

    const int T = c >> 5, lcc = c & 31;
    char* bh = Bh + T * 4096 + lcc * 32;
    char* bl = Bl + T * 4096 + lcc * 32;
#pragma unroll
    for (int ss = 0; ss < 4; ++ss)
#pragma unroll
        for (int h = 0; h < 2; ++h) {
            f16x8 ph, pl;
#pragma unroll
            for (int j = 0; j < 8; ++j) {
                float v = e[ss * 16 + h * 8 + j] * 256.0f;
                _Float16 hh = (_Float16)v;
                ph[j] = hh;
                pl[j] = (_Float16)(v - (float)hh);
            }
            *(f16x8*)(bh + ss * 1024 + h * 16) = ph;
            *(f16x8*)(bl + ss * 1024 + h * 16) = pl;
        }
}

// ---------- screen: 4-wave blocks, B streamed from L2, per-wave 32 rows
// acc = 1536 + 128*bn - 256*dot  (positive, guarded) -> u32 bit-min == argmin.
// Per-wave math byte-identical to R7; only workgroup packaging changed.
__launch_bounds__(256, 5)
__global__ void vq_screen(const float* __restrict__ x,
                          const char* __restrict__ Bh,
                          const char* __restrict__ Bl,
                          const float* __restrict__ nbs,
                          const float* __restrict__ emb,
                          float* __restrict__ out,
                          int* __restrict__ counts,
                          double* __restrict__ loss_sum,
                          u32* __restrict__ flagcnt,
                          u32* __restrict__ flaglist) {
    const int lane = threadIdx.x & 63;
    const int wid  = threadIdx.x >> 6;   // 4 waves x 32 rows = 128 rows/block
    const int lc = lane & 31;
    const int hi = lane >> 5;
    const int rbase = blockIdx.x * 128 + wid * 32;
    const int row = rbase + lc;

    // A fragments: slot j of k-step s = -x[row][16s + 8hi + j], fp16 hi/lo split
    f16x8 ah[4], al[4];
    float anh = 0.f;
    {
        const float* xr = x + (size_t)row * DIM + hi * 8;
#pragma unroll
        for (int s = 0; s < 4; ++s) {
            float4 u0 = *(const float4*)(xr + s * 16);
            float4 u1 = *(const float4*)(xr + s * 16 + 4);
            float v[8] = {u0.x, u0.y, u0.z, u0.w, u1.x, u1.y, u1.z, u1.w};
            f16x8 h8, l8;
#pragma unroll
            for (int j = 0; j < 8; ++j) {
                anh = fmaf(v[j], v[j], anh);
                float nv = -v[j];
                _Float16 hh = (_Float16)nv;
                h8[j] = hh;
                l8[j] = (_Float16)(nv - (float)hh);
            }
            ah[s] = h8; al[s] = l8;
        }
    }
    const float an = anh + __shfl_xor(anh, 32);

    u32 best[16], sec[16], bcol[16];
#pragma unroll
    for (int r = 0; r < 16; ++r) {
        best[r] = 0xFFFFFFFFu; sec[r] = 0xFFFFFFFFu; bcol[r] = 0u;
    }

    const char* bhp = Bh + lc * 32 + hi * 16;
    const char* blp = Bl + lc * 32 + hi * 16;

#pragma unroll 2
    for (int t = 0; t < 32; ++t) {
        const float nb = nbs[t * 32 + lc];
        const char* bh = bhp + t * 4096;
        const char* bl = blp + t * 4096;
        f32x16 acc;
#pragma unroll
        for (int r = 0; r < 16; ++r) acc[r] = nb;
#pragma unroll
        for (int s = 0; s < 4; ++s) {
            f16x8 vh = *(const f16x8*)(bh + s * 1024);
            f16x8 vl = *(const f16x8*)(bl + s * 1024);
            acc = __builtin_amdgcn_mfma_f32_32x32x16_f16(ah[s], vh, acc, 0, 0, 0);
            acc = __builtin_amdgcn_mfma_f32_32x32x16_f16(ah[s], vl, acc, 0, 0, 0);
            acc = __builtin_amdgcn_mfma_f32_32x32x16_f16(al[s], vh, acc, 0, 0, 0);
        }
        const u32 tl = (u32)(t * 32 + lc);
#pragma unroll
        for (int r = 0; r < 16; ++r) {
            u32 vb = __float_as_uint(acc[r]);      // positive -> monotone bits
            u32 mx = vb > best[r] ? vb : best[r];
            sec[r] = min(sec[r], mx);
            bool lt = vb < best[r];                // strict: first index wins
            bcol[r] = lt ? tl : bcol[r];
            best[r] = min(best[r], vb);
        }
    }

    // butterfly across the 32 code-lanes; packed u64 preserves min-col ties
    u64 bp[16];
#pragma unroll
    for (int r = 0; r < 16; ++r) bp[r] = ((u64)best[r] << 32) | bcol[r];
#pragma unroll
    for (int m = 1; m < 32; m <<= 1) {
#pragma unroll
        for (int r = 0; r < 16; ++r) {
            u64 o  = __shfl_xor(bp[r], m);
            u32 os = __shfl_xor(sec[r], m);
            u32 oh = (u32)(o >> 32);
            u32 mh = (u32)(bp[r] >> 32);
            u32 mx = mh > oh ? mh : oh;
            sec[r] = min(min(sec[r], os), mx);
            if (o < bp[r]) bp[r] = o;
        }
    }

    // fused gather: certify -> write out from emb + identity-loss; else flag
    double dsum = 0.0;
#pragma unroll
    for (int r = 0; r < 16; ++r) {
        const int rl = (r & 3) + 8 * (r >> 2) + 4 * hi;
        const int grow = rbase + rl;
        const float bv = __uint_as_float((u32)(bp[r] >> 32));
        const u32 col = (u32)bp[r];
        const float sv = __uint_as_float(sec[r]);
        const float anr = __shfl(an, rl);
        const float gap = sv - bv;
        const float T = fmaf(1e-4f, anr, 0.004f);
        const bool flg = (gap <= T) || (anr < 4.0f) || (anr > 5000.0f);
        if (!flg) {
            if (lc < 16) {   // 16 lanes x float4 = full 64B sectors
                float4 q = *(const float4*)(emb + (size_t)col * DIM + lc * 4);
                *(float4*)(out + (size_t)grow * DIM + lc * 4) = q;
            }
            if (lc == 0) {
                atomicAdd(&counts[col], 1);
                // loss via exact identity: dist = an + bn - 2 dot = (acc-1536)/128 + an
                float dist = fmaxf(fmaf(bv - 1536.0f, 0.0078125f, anr), 0.f);
                dsum += (double)dist;
            }
        } else if (lc == 0) {
            u32 idx = atomicAdd(flagcnt, 1u);
            flaglist[idx] = (u32)grow;
        }
    }
    dsum += __shfl_xor(dsum, 32);
    if (lane == 0) atomicAdd(loss_sum, dsum);
}

// ---------- rescan: block-per-flagged-row, exact fp32 argmin (R1 chains)
#define RS_GRID 4096
__launch_bounds__(256)
__global__ void vq_rescan(const float* __restrict__ x,
                          const float* __restrict__ emb,
                          const float* __restrict__ bn,
                          const u32* __restrict__ flagcnt,
                          const u32* __restrict__ flaglist,
                          float* __restrict__ out,
                          int* __restrict__ counts,
                          double* __restrict__ loss_sum) {
    __shared__ float Xs[DIM];
    __shared__ u64 wred[4];
    const u32 n = *flagcnt;
    const int t = threadIdx.x;

    for (u32 i = blockIdx.x; i < n; i += RS_GRID) {
        const int row = (int)flaglist[i];
        if (t < DIM) Xs[t] = x[(size_t)row * DIM + t];
        __syncthreads();

        float an = 0.f;
#pragma unroll
        for (int d = 0; d < DIM; ++d) an = fmaf(Xs[d], Xs[d], an);

        u64 bestp = ~0ull;
#pragma unroll
        for (int cc = 0; cc < 4; ++cc) {
            const int k = cc * 256 + t;
            const float* ek = emb + (size_t)k * DIM;
            float q0 = 0.f, q1 = 0.f, q2 = 0.f, q3 = 0.f;
#pragma unroll
            for (int d = 0; d < DIM; d += 4) {
                float4 ev = *(const float4*)(ek + d);
                q0 = fmaf(Xs[d],     ev.x, q0);
                q1 = fmaf(Xs[d + 1], ev.y, q1);
                q2 = fmaf(Xs[d + 2], ev.z, q2);
                q3 = fmaf(Xs[d + 3], ev.w, q3);
            }
            float dot = (q0 + q1) + (q2 + q3);
            float dist = fmaxf((an + bn[k]) - 2.0f * dot, 0.f);
            u64 p = ((u64)__float_as_uint(dist) << 32) | (u32)k;
            if (p < bestp) bestp = p;
        }
#pragma unroll
        for (int m = 1; m < 64; m <<= 1) {
            u64 o = __shfl_xor(bestp, m);
            if (o < bestp) bestp = o;
        }
        if ((t & 63) == 0) wred[t >> 6] = bestp;
        __syncthreads();
        u64 b = wred[0];
        if (wred[1] < b) b = wred[1];
        if (wred[2] < b) b = wred[2];
        if (wred[3] < b) b = wred[3];
        const int bk = (int)(u32)b;

        if (t < DIM) {
            float qv = emb[(size_t)bk * DIM + t];
            out[(size_t)row * DIM + t] = qv;
            float dx = qv - Xs[t];
            double ds = (double)(dx * dx);
#pragma unroll
            for (int m = 1; m < 64; m <<= 1) ds += __shfl_xor(ds, m);
            if (t == 0) {
                atomicAdd(loss_sum, ds);
                atomicAdd(&counts[bk], 1);
            }
        }
        __syncthreads();
    }
}

__global__ void vq_final_kernel(const int* __restrict__ counts,
                                const double* __restrict__ loss_sum,
                                float* __restrict__ out) {
    __shared__ double red[16];
    const int t = threadIdx.x;           // 1024 threads
    float p = (float)counts[t] / (float)N_ROWS;
    double term = (double)p * log((double)p + 1e-10);
#pragma unroll
    for (int off = 32; off > 0; off >>= 1) term += __shfl_down(term, off);
    if ((t & 63) == 0) red[t >> 6] = term;
    __syncthreads();
    if (t == 0) {
        double s = 0.0;
#pragma unroll
        for (int w = 0; w < 16; ++w) s += red[w];
        const size_t base = (size_t)N_ROWS * DIM;
        out[base]     = (float)(1.5 * (*loss_sum) / (double)((size_t)N_ROWS * DIM));
        out[base + 1] = (float)exp(-s);
    }
}

extern "C" void kernel_launch(void* const* d_in, const int* in_sizes, int n_in,
                              void* d_out, int out_size, void* d_ws, size_t ws_size,
                              hipStream_t stream) {
    const float* x   = (const float*)d_in[0];
    const float* emb = (const float*)d_in[1];
    float* out = (float*)d_out;

    char* ws = (char*)d_ws;
    double* loss_sum = (double*)ws;
    u32*  flagcnt  = (u32*)(ws + WS_FLAGCNT_OFF);
    int*  counts   = (int*)(ws + WS_COUNTS_OFF);
    float* bn      = (float*)(ws + WS_BN_OFF);
    float* nbs     = (float*)(ws + WS_NBS_OFF);
    char* Bh       = ws + WS_BH_OFF;
    char* Bl       = ws + WS_BL_OFF;
    u32*  flist    = (u32*)(ws + WS_FLIST_OFF);

    hipMemsetAsync(d_ws, 0, WS_ZERO_BYTES, stream);

    vq_prep<<<KCODES / 256, 256, 0, stream>>>(emb, bn, nbs, Bh, Bl);
    vq_screen<<<N_ROWS / 128, 256, 0, stream>>>(x, Bh, Bl, nbs, emb, out,
                                                counts, loss_sum, flagcnt, flist);
    vq_rescan<<<RS_GRID, 256, 0, stream>>>(x, emb, bn, flagcnt, flist,
                                           out, counts, loss_sum);
    vq_final_kernel<<<1, 1024, 0, stream>>>(counts, loss_sum, out);
}

// Round 9
// 238.406 us; speedup vs baseline: 1.6975x; 1.6975x over previous
//
#include <hip/hip_runtime.h>
#include <math.h>

#define N_ROWS (32 * 64 * 64)   // 131072 rows
#define KCODES 1024
#define DIM 64

typedef __attribute__((ext_vector_type(8))) _Float16 f16x8;
typedef __attribute__((ext_vector_type(16))) float f32x16;
typedef unsigned long long u64;
typedef unsigned int u32;

// d_ws layout:
//   0       double loss_sum
//   8       u32 flag_count
//   16      int counts[1024]            (-> 4112) [zeroed]
//   4352    float bn[1024]              exact chain norms
//   8448    float nbs[1024]             1536 + 128*bn (fp32)
//   16384   char Bh[128K]  fp16 hi codes, fragment-order [tile][s][lc*32+hi*16]
//   147456  char Bl[128K]  fp16 lo codes, same layout
//   278528  u32 flaglist[N_ROWS]
#define WS_FLAGCNT_OFF 8
#define WS_COUNTS_OFF  16
#define WS_BN_OFF      4352
#define WS_NBS_OFF     8448
#define WS_BH_OFF      16384
#define WS_BL_OFF      147456
#define WS_FLIST_OFF   278528
#define WS_ZERO_BYTES  4112

// ---------- prep: exact bn, MFMA C-init consts, fragment-ordered split codes
__global__ void vq_prep(const float* __restrict__ emb,
                        float* __restrict__ bn,
                        float* __restrict__ nbs,
                        char* __restrict__ Bh,
                        char* __restrict__ Bl) {
    int c = blockIdx.x * 256 + threadIdx.x;   // 4 blocks x 256 = 1024 codes
    const float* e = emb + (size_t)c * DIM;
    float s = 0.f;
#pragma unroll
    for (int d = 0; d < DIM; ++d) s = fmaf(e[d], e[d], s);
    bn[c] = s;
    nbs[c] = fmaf(s, 128.0f, 1536.0f);

    const int T = c >> 5, lcc = c & 31;
    char* bh = Bh + T * 4096 + lcc * 32;
    char* bl = Bl + T * 4096 + lcc * 32;
#pragma unroll
    for (int ss = 0; ss < 4; ++ss)
#pragma unroll
        for (int h = 0; h < 2; ++h) {
            f16x8 ph, pl;
#pragma unroll
            for (int j = 0; j < 8; ++j) {
                float v = e[ss * 16 + h * 8 + j] * 256.0f;
                _Float16 hh = (_Float16)v;
                ph[j] = hh;
                pl[j] = (_Float16)(v - (float)hh);
            }
            *(f16x8*)(bh + ss * 1024 + h * 16) = ph;
            *(f16x8*)(bl + ss * 1024 + h * 16) = pl;
        }
}

// ---------- screen: 4-wave blocks, B streamed from L2, per-wave 32 rows
// acc = 1536 + 128*bn - 256*dot  (positive, guarded) -> u32 bit-min == argmin.
// Math byte-identical to the 190us R7 kernel; launch_bounds(256,3): ~170-reg
// cap >> ~120-reg live set, so NO spill (R8's (256,5) cap at ~100 spilled
// everything: VGPR 48, FETCH 729MB scratch traffic).
__launch_bounds__(256, 3)
__global__ void vq_screen(const float* __restrict__ x,
                          const char* __restrict__ Bh,
                          const char* __restrict__ Bl,
                          const float* __restrict__ nbs,
                          const float* __restrict__ emb,
                          float* __restrict__ out,
                          int* __restrict__ counts,
                          double* __restrict__ loss_sum,
                          u32* __restrict__ flagcnt,
                          u32* __restrict__ flaglist) {
    const int lane = threadIdx.x & 63;
    const int wid  = threadIdx.x >> 6;   // 4 waves x 32 rows = 128 rows/block
    const int lc = lane & 31;
    const int hi = lane >> 5;
    const int rbase = blockIdx.x * 128 + wid * 32;
    const int row = rbase + lc;

    // A fragments: slot j of k-step s = -x[row][16s + 8hi + j], fp16 hi/lo split
    f16x8 ah[4], al[4];
    float anh = 0.f;
    {
        const float* xr = x + (size_t)row * DIM + hi * 8;
#pragma unroll
        for (int s = 0; s < 4; ++s) {
            float4 u0 = *(const float4*)(xr + s * 16);
            float4 u1 = *(const float4*)(xr + s * 16 + 4);
            float v[8] = {u0.x, u0.y, u0.z, u0.w, u1.x, u1.y, u1.z, u1.w};
            f16x8 h8, l8;
#pragma unroll
            for (int j = 0; j < 8; ++j) {
                anh = fmaf(v[j], v[j], anh);
                float nv = -v[j];
                _Float16 hh = (_Float16)nv;
                h8[j] = hh;
                l8[j] = (_Float16)(nv - (float)hh);
            }
            ah[s] = h8; al[s] = l8;
        }
    }
    const float an = anh + __shfl_xor(anh, 32);

    u32 best[16], sec[16], bcol[16];
#pragma unroll
    for (int r = 0; r < 16; ++r) {
        best[r] = 0xFFFFFFFFu; sec[r] = 0xFFFFFFFFu; bcol[r] = 0u;
    }

    const char* bhp = Bh + lc * 32 + hi * 16;
    const char* blp = Bl + lc * 32 + hi * 16;

#pragma unroll 2
    for (int t = 0; t < 32; ++t) {
        const float nb = nbs[t * 32 + lc];
        const char* bh = bhp + t * 4096;
        const char* bl = blp + t * 4096;
        f32x16 acc;
#pragma unroll
        for (int r = 0; r < 16; ++r) acc[r] = nb;
#pragma unroll
        for (int s = 0; s < 4; ++s) {
            f16x8 vh = *(const f16x8*)(bh + s * 1024);
            f16x8 vl = *(const f16x8*)(bl + s * 1024);
            acc = __builtin_amdgcn_mfma_f32_32x32x16_f16(ah[s], vh, acc, 0, 0, 0);
            acc = __builtin_amdgcn_mfma_f32_32x32x16_f16(ah[s], vl, acc, 0, 0, 0);
            acc = __builtin_amdgcn_mfma_f32_32x32x16_f16(al[s], vh, acc, 0, 0, 0);
        }
        const u32 tl = (u32)(t * 32 + lc);
#pragma unroll
        for (int r = 0; r < 16; ++r) {
            u32 vb = __float_as_uint(acc[r]);      // positive -> monotone bits
            u32 mx = vb > best[r] ? vb : best[r];
            sec[r] = min(sec[r], mx);
            bool lt = vb < best[r];                // strict: first index wins
            bcol[r] = lt ? tl : bcol[r];
            best[r] = min(best[r], vb);
        }
    }

    // butterfly across the 32 code-lanes; packed u64 preserves min-col ties
    u64 bp[16];
#pragma unroll
    for (int r = 0; r < 16; ++r) bp[r] = ((u64)best[r] << 32) | bcol[r];
#pragma unroll
    for (int m = 1; m < 32; m <<= 1) {
#pragma unroll
        for (int r = 0; r < 16; ++r) {
            u64 o  = __shfl_xor(bp[r], m);
            u32 os = __shfl_xor(sec[r], m);
            u32 oh = (u32)(o >> 32);
            u32 mh = (u32)(bp[r] >> 32);
            u32 mx = mh > oh ? mh : oh;
            sec[r] = min(min(sec[r], os), mx);
            if (o < bp[r]) bp[r] = o;
        }
    }

    // fused gather: certify -> write out from emb + identity-loss; else flag
    double dsum = 0.0;
#pragma unroll
    for (int r = 0; r < 16; ++r) {
        const int rl = (r & 3) + 8 * (r >> 2) + 4 * hi;
        const int grow = rbase + rl;
        const float bv = __uint_as_float((u32)(bp[r] >> 32));
        const u32 col = (u32)bp[r];
        const float sv = __uint_as_float(sec[r]);
        const float anr = __shfl(an, rl);
        const float gap = sv - bv;
        const float T = fmaf(1e-4f, anr, 0.004f);
        const bool flg = (gap <= T) || (anr < 4.0f) || (anr > 5000.0f);
        if (!flg) {
            if (lc < 16) {   // 16 lanes x float4 = full 64B sectors
                float4 q = *(const float4*)(emb + (size_t)col * DIM + lc * 4);
                *(float4*)(out + (size_t)grow * DIM + lc * 4) = q;
            }
            if (lc == 0) {
                atomicAdd(&counts[col], 1);
                // loss via exact identity: dist = an + bn - 2 dot = (acc-1536)/128 + an
                float dist = fmaxf(fmaf(bv - 1536.0f, 0.0078125f, anr), 0.f);
                dsum += (double)dist;
            }
        } else if (lc == 0) {
            u32 idx = atomicAdd(flagcnt, 1u);
            flaglist[idx] = (u32)grow;
        }
    }
    dsum += __shfl_xor(dsum, 32);
    if (lane == 0) atomicAdd(loss_sum, dsum);
}

// ---------- rescan: block-per-flagged-row, exact fp32 argmin (R1 chains)
#define RS_GRID 4096
__launch_bounds__(256)
__global__ void vq_rescan(const float* __restrict__ x,
                          const float* __restrict__ emb,
                          const float* __restrict__ bn,
                          const u32* __restrict__ flagcnt,
                          const u32* __restrict__ flaglist,
                          float* __restrict__ out,
                          int* __restrict__ counts,
                          double* __restrict__ loss_sum) {
    __shared__ float Xs[DIM];
    __shared__ u64 wred[4];
    const u32 n = *flagcnt;
    const int t = threadIdx.x;

    for (u32 i = blockIdx.x; i < n; i += RS_GRID) {
        const int row = (int)flaglist[i];
        if (t < DIM) Xs[t] = x[(size_t)row * DIM + t];
        __syncthreads();

        float an = 0.f;
#pragma unroll
        for (int d = 0; d < DIM; ++d) an = fmaf(Xs[d], Xs[d], an);

        u64 bestp = ~0ull;
#pragma unroll
        for (int cc = 0; cc < 4; ++cc) {
            const int k = cc * 256 + t;
            const float* ek = emb + (size_t)k * DIM;
            float q0 = 0.f, q1 = 0.f, q2 = 0.f, q3 = 0.f;
#pragma unroll
            for (int d = 0; d < DIM; d += 4) {
                float4 ev = *(const float4*)(ek + d);
                q0 = fmaf(Xs[d],     ev.x, q0);
                q1 = fmaf(Xs[d + 1], ev.y, q1);
                q2 = fmaf(Xs[d + 2], ev.z, q2);
                q3 = fmaf(Xs[d + 3], ev.w, q3);
            }
            float dot = (q0 + q1) + (q2 + q3);
            float dist = fmaxf((an + bn[k]) - 2.0f * dot, 0.f);
            u64 p = ((u64)__float_as_uint(dist) << 32) | (u32)k;
            if (p < bestp) bestp = p;
        }
#pragma unroll
        for (int m = 1; m < 64; m <<= 1) {
            u64 o = __shfl_xor(bestp, m);
            if (o < bestp) bestp = o;
        }
        if ((t & 63) == 0) wred[t >> 6] = bestp;
        __syncthreads();
        u64 b = wred[0];
        if (wred[1] < b) b = wred[1];
        if (wred[2] < b) b = wred[2];
        if (wred[3] < b) b = wred[3];
        const int bk = (int)(u32)b;

        if (t < DIM) {
            float qv = emb[(size_t)bk * DIM + t];
            out[(size_t)row * DIM + t] = qv;
            float dx = qv - Xs[t];
            double ds = (double)(dx * dx);
#pragma unroll
            for (int m = 1; m < 64; m <<= 1) ds += __shfl_xor(ds, m);
            if (t == 0) {
                atomicAdd(loss_sum, ds);
                atomicAdd(&counts[bk], 1);
            }
        }
        __syncthreads();
    }
}

__global__ void vq_final_kernel(const int* __restrict__ counts,
                                const double* __restrict__ loss_sum,
                                float* __restrict__ out) {
    __shared__ double red[16];
    const int t = threadIdx.x;           // 1024 threads
    float p = (float)counts[t] / (float)N_ROWS;
    double term = (double)p * log((double)p + 1e-10);
#pragma unroll
    for (int off = 32; off > 0; off >>= 1) term += __shfl_down(term, off);
    if ((t & 63) == 0) red[t >> 6] = term;
    __syncthreads();
    if (t == 0) {
        double s = 0.0;
#pragma unroll
        for (int w = 0; w < 16; ++w) s += red[w];
        const size_t base = (size_t)N_ROWS * DIM;
        out[base]     = (float)(1.5 * (*loss_sum) / (double)((size_t)N_ROWS * DIM));
        out[base + 1] = (float)exp(-s);
    }
}

extern "C" void kernel_launch(void* const* d_in, const int* in_sizes, int n_in,
                              void* d_out, int out_size, void* d_ws, size_t ws_size,
                              hipStream_t stream) {
    const float* x   = (const float*)d_in[0];
    const float* emb = (const float*)d_in[1];
    float* out = (float*)d_out;

    char* ws = (char*)d_ws;
    double* loss_sum = (double*)ws;
    u32*  flagcnt  = (u32*)(ws + WS_FLAGCNT_OFF);
    int*  counts   = (int*)(ws + WS_COUNTS_OFF);
    float* bn      = (float*)(ws + WS_BN_OFF);
    float* nbs     = (float*)(ws + WS_NBS_OFF);
    char* Bh       = ws + WS_BH_OFF;
    char* Bl       = ws + WS_BL_OFF;
    u32*  flist    = (u32*)(ws + WS_FLIST_OFF);

    hipMemsetAsync(d_ws, 0, WS_ZERO_BYTES, stream);

    vq_prep<<<KCODES / 256, 256, 0, stream>>>(emb, bn, nbs, Bh, Bl);
    vq_screen<<<N_ROWS / 128, 256, 0, stream>>>(x, Bh, Bl, nbs, emb, out,
                                                counts, loss_sum, flagcnt, flist);
    vq_rescan<<<RS_GRID, 256, 0, stream>>>(x, emb, bn, flagcnt, flist,
                                           out, counts, loss_sum);
    vq_final_kernel<<<1, 1024, 0, stream>>>(counts, loss_sum, out);
}

// Round 10
// 220.916 us; speedup vs baseline: 1.8319x; 1.0792x over previous
//
#include <hip/hip_runtime.h>
#include <math.h>

#define N_ROWS (32 * 64 * 64)   // 131072 rows
#define KCODES 1024
#define DIM 64

typedef __attribute__((ext_vector_type(8))) _Float16 f16x8;
typedef __attribute__((ext_vector_type(16))) float f32x16;
typedef unsigned long long u64;
typedef unsigned int u32;

// d_ws layout:
//   0       double loss_sum
//   8       u32 flag_count
//   16      int counts[1024]            (-> 4112) [zeroed]
//   4352    float bn[1024]              exact chain norms
//   8448    float nbs[1024]             1536 + 128*bn (fp32)
//   16384   char Bh[128K]  fp16 hi codes, fragment-order [tile][s][lc*32+hi*16]
//   147456  char Bl[128K]  fp16 lo codes, same layout
//   278528  u32 flaglist[N_ROWS]
#define WS_FLAGCNT_OFF 8
#define WS_COUNTS_OFF  16
#define WS_BN_OFF      4352
#define WS_NBS_OFF     8448
#define WS_BH_OFF      16384
#define WS_BL_OFF      147456
#define WS_FLIST_OFF   278528
#define WS_ZERO_BYTES  4112

// ---------- prep: exact bn, MFMA C-init consts, fragment-ordered split codes
__global__ void vq_prep(const float* __restrict__ emb,
                        float* __restrict__ bn,
                        float* __restrict__ nbs,
                        char* __restrict__ Bh,
                        char* __restrict__ Bl) {
    int c = blockIdx.x * 256 + threadIdx.x;   // 4 blocks x 256 = 1024 codes
    const float* e = emb + (size_t)c * DIM;
    float s = 0.f;
#pragma unroll
    for (int d = 0; d < DIM; ++d) s = fmaf(e[d], e[d], s);
    bn[c] = s;
    nbs[c] = fmaf(s, 128.0f, 1536.0f);

    const int T = c >> 5, lcc = c & 31;
    char* bh = Bh + T * 4096 + lcc * 32;
    char* bl = Bl + T * 4096 + lcc * 32;
#pragma unroll
    for (int ss = 0; ss < 4; ++ss)
#pragma unroll
        for (int h = 0; h < 2; ++h) {
            f16x8 ph, pl;
#pragma unroll
            for (int j = 0; j < 8; ++j) {
                float v = e[ss * 16 + h * 8 + j] * 256.0f;
                _Float16 hh = (_Float16)v;
                ph[j] = hh;
                pl[j] = (_Float16)(v - (float)hh);
            }
            *(f16x8*)(bh + ss * 1024 + h * 16) = ph;
            *(f16x8*)(bl + ss * 1024 + h * 16) = pl;
        }
}

// load tile tt's 8 B-vectors + its nbs value into named regs (static indexing)
#define LOAD_TILE(H0,H1,H2,H3,L0,L1,L2,L3,NB, tt) do {            \
    const char* _bh = bhp + (tt) * 4096;                          \
    const char* _bl = blp + (tt) * 4096;                          \
    H0 = *(const f16x8*)(_bh +    0);                             \
    H1 = *(const f16x8*)(_bh + 1024);                             \
    H2 = *(const f16x8*)(_bh + 2048);                             \
    H3 = *(const f16x8*)(_bh + 3072);                             \
    L0 = *(const f16x8*)(_bl +    0);                             \
    L1 = *(const f16x8*)(_bl + 1024);                             \
    L2 = *(const f16x8*)(_bl + 2048);                             \
    L3 = *(const f16x8*)(_bl + 3072);                             \
    NB = nbs[(tt) * 32 + lc];                                     \
} while (0)

// compute tile tt from named regs: 12 MFMA (same order as R7/R9) + tracking
#define COMPUTE_TILE(H0,H1,H2,H3,L0,L1,L2,L3,NB, tt) do {                      \
    f32x16 acc;                                                                \
    _Pragma("unroll")                                                          \
    for (int r = 0; r < 16; ++r) acc[r] = NB;                                  \
    acc = __builtin_amdgcn_mfma_f32_32x32x16_f16(ah[0], H0, acc, 0, 0, 0);     \
    acc = __builtin_amdgcn_mfma_f32_32x32x16_f16(ah[0], L0, acc, 0, 0, 0);     \
    acc = __builtin_amdgcn_mfma_f32_32x32x16_f16(al[0], H0, acc, 0, 0, 0);     \
    acc = __builtin_amdgcn_mfma_f32_32x32x16_f16(ah[1], H1, acc, 0, 0, 0);     \
    acc = __builtin_amdgcn_mfma_f32_32x32x16_f16(ah[1], L1, acc, 0, 0, 0);     \
    acc = __builtin_amdgcn_mfma_f32_32x32x16_f16(al[1], H1, acc, 0, 0, 0);     \
    acc = __builtin_amdgcn_mfma_f32_32x32x16_f16(ah[2], H2, acc, 0, 0, 0);     \
    acc = __builtin_amdgcn_mfma_f32_32x32x16_f16(ah[2], L2, acc, 0, 0, 0);     \
    acc = __builtin_amdgcn_mfma_f32_32x32x16_f16(al[2], H2, acc, 0, 0, 0);     \
    acc = __builtin_amdgcn_mfma_f32_32x32x16_f16(ah[3], H3, acc, 0, 0, 0);     \
    acc = __builtin_amdgcn_mfma_f32_32x32x16_f16(ah[3], L3, acc, 0, 0, 0);     \
    acc = __builtin_amdgcn_mfma_f32_32x32x16_f16(al[3], H3, acc, 0, 0, 0);     \
    const u32 tl = (u32)((tt) * 32 + lc);                                      \
    _Pragma("unroll")                                                          \
    for (int r = 0; r < 16; ++r) {                                             \
        u32 vb = __float_as_uint(acc[r]);                                      \
        u32 mx = vb > best[r] ? vb : best[r];                                  \
        sec[r] = min(sec[r], mx);                                              \
        bool lt = vb < best[r];                                                \
        bcol[r] = lt ? tl : bcol[r];                                           \
        best[r] = min(best[r], vb);                                            \
    }                                                                          \
} while (0)

// ---------- screen: 4-wave blocks, B streamed from L2 with REGISTER
// double-buffer (prefetch tile t+1 during tile t's MFMA+epilogue).
// acc = 1536 + 128*bn - 256*dot (positive, guarded) -> u32 bit-min == argmin.
// launch_bounds(256,2): 256-reg ceiling = spill-proof; actual ~160 regs
// still admits 3 waves/SIMD.
__launch_bounds__(256, 2)
__global__ void vq_screen(const float* __restrict__ x,
                          const char* __restrict__ Bh,
                          const char* __restrict__ Bl,
                          const float* __restrict__ nbs,
                          const float* __restrict__ emb,
                          float* __restrict__ out,
                          int* __restrict__ counts,
                          double* __restrict__ loss_sum,
                          u32* __restrict__ flagcnt,
                          u32* __restrict__ flaglist) {
    const int lane = threadIdx.x & 63;
    const int wid  = threadIdx.x >> 6;   // 4 waves x 32 rows = 128 rows/block
    const int lc = lane & 31;
    const int hi = lane >> 5;
    const int rbase = blockIdx.x * 128 + wid * 32;
    const int row = rbase + lc;

    // A fragments: slot j of k-step s = -x[row][16s + 8hi + j], fp16 hi/lo split
    f16x8 ah[4], al[4];
    float anh = 0.f;
    {
        const float* xr = x + (size_t)row * DIM + hi * 8;
#pragma unroll
        for (int s = 0; s < 4; ++s) {
            float4 u0 = *(const float4*)(xr + s * 16);
            float4 u1 = *(const float4*)(xr + s * 16 + 4);
            float v[8] = {u0.x, u0.y, u0.z, u0.w, u1.x, u1.y, u1.z, u1.w};
            f16x8 h8, l8;
#pragma unroll
            for (int j = 0; j < 8; ++j) {
                anh = fmaf(v[j], v[j], anh);
                float nv = -v[j];
                _Float16 hh = (_Float16)nv;
                h8[j] = hh;
                l8[j] = (_Float16)(nv - (float)hh);
            }
            ah[s] = h8; al[s] = l8;
        }
    }
    const float an = anh + __shfl_xor(anh, 32);

    u32 best[16], sec[16], bcol[16];
#pragma unroll
    for (int r = 0; r < 16; ++r) {
        best[r] = 0xFFFFFFFFu; sec[r] = 0xFFFFFFFFu; bcol[r] = 0u;
    }

    const char* bhp = Bh + lc * 32 + hi * 16;
    const char* blp = Bl + lc * 32 + hi * 16;

    // register double-buffer: A = even tiles, B = odd tiles
    f16x8 aH0, aH1, aH2, aH3, aL0, aL1, aL2, aL3;
    f16x8 bH0, bH1, bH2, bH3, bL0, bL1, bL2, bL3;
    float nbA, nbB;

    LOAD_TILE(aH0, aH1, aH2, aH3, aL0, aL1, aL2, aL3, nbA, 0);

    for (int t = 0; t < 32; t += 2) {
        const int t1 = t + 1;                      // <= 31
        const int t2 = (t + 2 < 32) ? t + 2 : 31;  // clamped (redundant last)
        LOAD_TILE(bH0, bH1, bH2, bH3, bL0, bL1, bL2, bL3, nbB, t1);
        COMPUTE_TILE(aH0, aH1, aH2, aH3, aL0, aL1, aL2, aL3, nbA, t);
        LOAD_TILE(aH0, aH1, aH2, aH3, aL0, aL1, aL2, aL3, nbA, t2);
        COMPUTE_TILE(bH0, bH1, bH2, bH3, bL0, bL1, bL2, bL3, nbB, t1);
    }

    // butterfly across the 32 code-lanes; packed u64 preserves min-col ties
    u64 bp[16];
#pragma unroll
    for (int r = 0; r < 16; ++r) bp[r] = ((u64)best[r] << 32) | bcol[r];
#pragma unroll
    for (int m = 1; m < 32; m <<= 1) {
#pragma unroll
        for (int r = 0; r < 16; ++r) {
            u64 o  = __shfl_xor(bp[r], m);
            u32 os = __shfl_xor(sec[r], m);
            u32 oh = (u32)(o >> 32);
            u32 mh = (u32)(bp[r] >> 32);
            u32 mx = mh > oh ? mh : oh;
            sec[r] = min(min(sec[r], os), mx);
            if (o < bp[r]) bp[r] = o;
        }
    }

    // fused gather: certify -> write out from emb + identity-loss; else flag
    double dsum = 0.0;
#pragma unroll
    for (int r = 0; r < 16; ++r) {
        const int rl = (r & 3) + 8 * (r >> 2) + 4 * hi;
        const int grow = rbase + rl;
        const float bv = __uint_as_float((u32)(bp[r] >> 32));
        const u32 col = (u32)bp[r];
        const float sv = __uint_as_float(sec[r]);
        const float anr = __shfl(an, rl);
        const float gap = sv - bv;
        const float T = fmaf(1e-4f, anr, 0.004f);
        const bool flg = (gap <= T) || (anr < 4.0f) || (anr > 5000.0f);
        if (!flg) {
            if (lc < 16) {   // 16 lanes x float4 = full 64B sectors
                float4 q = *(const float4*)(emb + (size_t)col * DIM + lc * 4);
                *(float4*)(out + (size_t)grow * DIM + lc * 4) = q;
            }
            if (lc == 0) {
                atomicAdd(&counts[col], 1);
                // loss via exact identity: dist = an + bn - 2 dot = (acc-1536)/128 + an
                float dist = fmaxf(fmaf(bv - 1536.0f, 0.0078125f, anr), 0.f);
                dsum += (double)dist;
            }
        } else if (lc == 0) {
            u32 idx = atomicAdd(flagcnt, 1u);
            flaglist[idx] = (u32)grow;
        }
    }
    dsum += __shfl_xor(dsum, 32);
    if (lane == 0) atomicAdd(loss_sum, dsum);
}

// ---------- rescan: block-per-flagged-row, exact fp32 argmin (R1 chains)
#define RS_GRID 4096
__launch_bounds__(256)
__global__ void vq_rescan(const float* __restrict__ x,
                          const float* __restrict__ emb,
                          const float* __restrict__ bn,
                          const u32* __restrict__ flagcnt,
                          const u32* __restrict__ flaglist,
                          float* __restrict__ out,
                          int* __restrict__ counts,
                          double* __restrict__ loss_sum) {
    __shared__ float Xs[DIM];
    __shared__ u64 wred[4];
    const u32 n = *flagcnt;
    const int t = threadIdx.x;

    for (u32 i = blockIdx.x; i < n; i += RS_GRID) {
        const int row = (int)flaglist[i];
        if (t < DIM) Xs[t] = x[(size_t)row * DIM + t];
        __syncthreads();

        float an = 0.f;
#pragma unroll
        for (int d = 0; d < DIM; ++d) an = fmaf(Xs[d], Xs[d], an);

        u64 bestp = ~0ull;
#pragma unroll
        for (int cc = 0; cc < 4; ++cc) {
            const int k = cc * 256 + t;
            const float* ek = emb + (size_t)k * DIM;
            float q0 = 0.f, q1 = 0.f, q2 = 0.f, q3 = 0.f;
#pragma unroll
            for (int d = 0; d < DIM; d += 4) {
                float4 ev = *(const float4*)(ek + d);
                q0 = fmaf(Xs[d],     ev.x, q0);
                q1 = fmaf(Xs[d + 1], ev.y, q1);
                q2 = fmaf(Xs[d + 2], ev.z, q2);
                q3 = fmaf(Xs[d + 3], ev.w, q3);
            }
            float dot = (q0 + q1) + (q2 + q3);
            float dist = fmaxf((an + bn[k]) - 2.0f * dot, 0.f);
            u64 p = ((u64)__float_as_uint(dist) << 32) | (u32)k;
            if (p < bestp) bestp = p;
        }
#pragma unroll
        for (int m = 1; m < 64; m <<= 1) {
            u64 o = __shfl_xor(bestp, m);
            if (o < bestp) bestp = o;
        }
        if ((t & 63) == 0) wred[t >> 6] = bestp;
        __syncthreads();
        u64 b = wred[0];
        if (wred[1] < b) b = wred[1];
        if (wred[2] < b) b = wred[2];
        if (wred[3] < b) b = wred[3];
        const int bk = (int)(u32)b;

        if (t < DIM) {
            float qv = emb[(size_t)bk * DIM + t];
            out[(size_t)row * DIM + t] = qv;
            float dx = qv - Xs[t];
            double ds = (double)(dx * dx);
#pragma unroll
            for (int m = 1; m < 64; m <<= 1) ds += __shfl_xor(ds, m);
            if (t == 0) {
                atomicAdd(loss_sum, ds);
                atomicAdd(&counts[bk], 1);
            }
        }
        __syncthreads();
    }
}

__global__ void vq_final_kernel(const int* __restrict__ counts,
                                const double* __restrict__ loss_sum,
                                float* __restrict__ out) {
    __shared__ double red[16];
    const int t = threadIdx.x;           // 1024 threads
    float p = (float)counts[t] / (float)N_ROWS;
    double term = (double)p * log((double)p + 1e-10);
#pragma unroll
    for (int off = 32; off > 0; off >>= 1) term += __shfl_down(term, off);
    if ((t & 63) == 0) red[t >> 6] = term;
    __syncthreads();
    if (t == 0) {
        double s = 0.0;
#pragma unroll
        for (int w = 0; w < 16; ++w) s += red[w];
        const size_t base = (size_t)N_ROWS * DIM;
        out[base]     = (float)(1.5 * (*loss_sum) / (double)((size_t)N_ROWS * DIM));
        out[base + 1] = (float)exp(-s);
    }
}

extern "C" void kernel_launch(void* const* d_in, const int* in_sizes, int n_in,
                              void* d_out, int out_size, void* d_ws, size_t ws_size,
                              hipStream_t stream) {
    const float* x   = (const float*)d_in[0];
    const float* emb = (const float*)d_in[1];
    float* out = (float*)d_out;

    char* ws = (char*)d_ws;
    double* loss_sum = (double*)ws;
    u32*  flagcnt  = (u32*)(ws + WS_FLAGCNT_OFF);
    int*  counts   = (int*)(ws + WS_COUNTS_OFF);
    float* bn      = (float*)(ws + WS_BN_OFF);
    float* nbs     = (float*)(ws + WS_NBS_OFF);
    char* Bh       = ws + WS_BH_OFF;
    char* Bl       = ws + WS_BL_OFF;
    u32*  flist    = (u32*)(ws + WS_FLIST_OFF);

    hipMemsetAsync(d_ws, 0, WS_ZERO_BYTES, stream);

    vq_prep<<<KCODES / 256, 256, 0, stream>>>(emb, bn, nbs, Bh, Bl);
    vq_screen<<<N_ROWS / 128, 256, 0, stream>>>(x, Bh, Bl, nbs, emb, out,
                                                counts, loss_sum, flagcnt, flist);
    vq_rescan<<<RS_GRID, 256, 0, stream>>>(x, emb, bn, flagcnt, flist,
                                           out, counts, loss_sum);
    vq_final_kernel<<<1, 1024, 0, stream>>>(counts, loss_sum, out);
}

// Round 11
// 199.903 us; speedup vs baseline: 2.0244x; 1.1051x over previous
//
#include <hip/hip_runtime.h>
#include <math.h>

#define N_ROWS (32 * 64 * 64)   // 131072 rows
#define KCODES 1024
#define DIM 64
#define NCHUNK 16               // 64 codes per chunk

typedef __attribute__((ext_vector_type(8))) _Float16 f16x8;
typedef __attribute__((ext_vector_type(16))) float f32x16;
typedef unsigned long long u64;
typedef unsigned int u32;

// d_ws layout:
//   0       double loss_sum
//   8       u32 flag_count
//   16      int counts[1024]            (-> 4112) [zeroed]
//   4352    float bn[1024]              exact chain norms
//   8448    float nbs[1024]             1536 + 128*bn (fp32)
//   16384   char Bc[16][16384]          per-chunk: [0,8K)=hi, [8K,16K)=lo,
//                                       byte (tt*4+s)*1024 + lc*32 + h*16 + j*2
//   278528  u32 flaglist[N_ROWS]
#define WS_FLAGCNT_OFF 8
#define WS_COUNTS_OFF  16
#define WS_BN_OFF      4352
#define WS_NBS_OFF     8448
#define WS_BC_OFF      16384
#define WS_FLIST_OFF   278528
#define WS_ZERO_BYTES  4112

__device__ inline void gload_lds16(const void* g, void* l) {
    __builtin_amdgcn_global_load_lds(
        (const __attribute__((address_space(1))) unsigned int*)g,
        (__attribute__((address_space(3))) unsigned int*)l,
        16, 0, 0);
}

// ---------- prep: exact bn, C-init consts, chunk-major fragment-order codes
__global__ void vq_prep(const float* __restrict__ emb,
                        float* __restrict__ bn,
                        float* __restrict__ nbs,
                        char* __restrict__ Bc) {
    int c = blockIdx.x * 256 + threadIdx.x;   // 4 blocks x 256 = 1024 codes
    const float* e = emb + (size_t)c * DIM;
    float s = 0.f;
#pragma unroll
    for (int d = 0; d < DIM; ++d) s = fmaf(e[d], e[d], s);
    bn[c] = s;
    nbs[c] = fmaf(s, 128.0f, 1536.0f);

    const int ch = c >> 6, tt = (c >> 5) & 1, lcc = c & 31;
    char* dst = Bc + (size_t)ch * 16384;
#pragma unroll
    for (int ss = 0; ss < 4; ++ss)
#pragma unroll
        for (int h = 0; h < 2; ++h) {
            f16x8 ph, pl;
#pragma unroll
            for (int j = 0; j < 8; ++j) {
                float v = e[ss * 16 + h * 8 + j] * 256.0f;
                _Float16 hh = (_Float16)v;
                ph[j] = hh;
                pl[j] = (_Float16)(v - (float)hh);
            }
            const int off = (tt * 4 + ss) * 1024 + lcc * 32 + h * 16;
            *(f16x8*)(dst + off)        = ph;
            *(f16x8*)(dst + 8192 + off) = pl;
        }
}

// issue async copy of chunk (c) into LDS buffer b: 4 x (256 lanes x 16B)
#define STAGE(b, c) do {                                                  \
    const char* _g = Bc + (size_t)(c) * 16384 + tid * 16;                 \
    char* _l = &LB[b][(tid >> 6) * 1024];   /* wave-uniform base */       \
    _Pragma("unroll")                                                     \
    for (int _j = 0; _j < 4; ++_j)                                        \
        gload_lds16(_g + _j * 4096, _l + _j * 4096);                      \
} while (0)

// ---------- screen: 4-wave blocks, LDS-shared B, async dbuf staging.
// acc = 1536 + 128*bn - 256*dot (positive, guarded) -> u32 bit-min == argmin.
// Per-(row,code) math byte-identical to R10 (same MFMA order, tracking,
// certification); only the B transport changed (L2-stream -> LDS-shared).
__launch_bounds__(256, 3)
__global__ void vq_screen(const float* __restrict__ x,
                          const char* __restrict__ Bc,
                          const float* __restrict__ nbs,
                          const float* __restrict__ emb,
                          float* __restrict__ out,
                          int* __restrict__ counts,
                          double* __restrict__ loss_sum,
                          u32* __restrict__ flagcnt,
                          u32* __restrict__ flaglist) {
    __shared__ __align__(16) char LB[2][16384];

    const int tid  = threadIdx.x;
    const int lane = tid & 63;
    const int wid  = tid >> 6;           // 4 waves x 32 rows = 128 rows/block
    const int lc = lane & 31;
    const int hi = lane >> 5;
    const int rbase = blockIdx.x * 128 + wid * 32;
    const int row = rbase + lc;

    // A fragments: slot j of k-step s = -x[row][16s + 8hi + j], fp16 hi/lo split
    f16x8 ah[4], al[4];
    float anh = 0.f;
    {
        const float* xr = x + (size_t)row * DIM + hi * 8;
#pragma unroll
        for (int s = 0; s < 4; ++s) {
            float4 u0 = *(const float4*)(xr + s * 16);
            float4 u1 = *(const float4*)(xr + s * 16 + 4);
            float v[8] = {u0.x, u0.y, u0.z, u0.w, u1.x, u1.y, u1.z, u1.w};
            f16x8 h8, l8;
#pragma unroll
            for (int j = 0; j < 8; ++j) {
                anh = fmaf(v[j], v[j], anh);
                float nv = -v[j];
                _Float16 hh = (_Float16)nv;
                h8[j] = hh;
                l8[j] = (_Float16)(nv - (float)hh);
            }
            ah[s] = h8; al[s] = l8;
        }
    }
    const float an = anh + __shfl_xor(anh, 32);

    u32 best[16], sec[16], bcol[16];
#pragma unroll
    for (int r = 0; r < 16; ++r) {
        best[r] = 0xFFFFFFFFu; sec[r] = 0xFFFFFFFFu; bcol[r] = 0u;
    }

    // prologue: stage chunk 0, barrier (drains vmcnt -> LDS valid)
    STAGE(0, 0);
    __syncthreads();

    for (int c = 0; c < NCHUNK; ++c) {
        const int b = c & 1;
        if (c + 1 < NCHUNK) STAGE(b ^ 1, c + 1);   // overlap with compute
        const char* base = LB[b];

#pragma unroll
        for (int tt = 0; tt < 2; ++tt) {
            const float nb = nbs[c * 64 + tt * 32 + lc];
            f32x16 acc;
#pragma unroll
            for (int r = 0; r < 16; ++r) acc[r] = nb;
#pragma unroll
            for (int s = 0; s < 4; ++s) {
                const int off = (tt * 4 + s) * 1024 + lc * 32 + hi * 16;
                f16x8 vh = *(const f16x8*)(base + off);
                f16x8 vl = *(const f16x8*)(base + 8192 + off);
                acc = __builtin_amdgcn_mfma_f32_32x32x16_f16(ah[s], vh, acc, 0, 0, 0);
                acc = __builtin_amdgcn_mfma_f32_32x32x16_f16(ah[s], vl, acc, 0, 0, 0);
                acc = __builtin_amdgcn_mfma_f32_32x32x16_f16(al[s], vh, acc, 0, 0, 0);
            }
            const u32 tl = (u32)(c * 64 + tt * 32 + lc);
#pragma unroll
            for (int r = 0; r < 16; ++r) {
                u32 vb = __float_as_uint(acc[r]);  // positive -> monotone bits
                u32 mx = vb > best[r] ? vb : best[r];
                sec[r] = min(sec[r], mx);
                bool lt = vb < best[r];            // strict: first index wins
                bcol[r] = lt ? tl : bcol[r];
                best[r] = min(best[r], vb);
            }
        }
        __syncthreads();   // next-chunk staged + all waves done with buf b
    }

    // butterfly across the 32 code-lanes; packed u64 preserves min-col ties
    u64 bp[16];
#pragma unroll
    for (int r = 0; r < 16; ++r) bp[r] = ((u64)best[r] << 32) | bcol[r];
#pragma unroll
    for (int m = 1; m < 32; m <<= 1) {
#pragma unroll
        for (int r = 0; r < 16; ++r) {
            u64 o  = __shfl_xor(bp[r], m);
            u32 os = __shfl_xor(sec[r], m);
            u32 oh = (u32)(o >> 32);
            u32 mh = (u32)(bp[r] >> 32);
            u32 mx = mh > oh ? mh : oh;
            sec[r] = min(min(sec[r], os), mx);
            if (o < bp[r]) bp[r] = o;
        }
    }

    // fused gather: certify -> write out from emb + identity-loss; else flag
    double dsum = 0.0;
#pragma unroll
    for (int r = 0; r < 16; ++r) {
        const int rl = (r & 3) + 8 * (r >> 2) + 4 * hi;
        const int grow = rbase + rl;
        const float bv = __uint_as_float((u32)(bp[r] >> 32));
        const u32 col = (u32)bp[r];
        const float sv = __uint_as_float(sec[r]);
        const float anr = __shfl(an, rl);
        const float gap = sv - bv;
        const float T = fmaf(1e-4f, anr, 0.004f);
        const bool flg = (gap <= T) || (anr < 4.0f) || (anr > 5000.0f);
        if (!flg) {
            if (lc < 16) {   // 16 lanes x float4 = full 64B sectors
                float4 q = *(const float4*)(emb + (size_t)col * DIM + lc * 4);
                *(float4*)(out + (size_t)grow * DIM + lc * 4) = q;
            }
            if (lc == 0) {
                atomicAdd(&counts[col], 1);
                // loss via exact identity: dist = an + bn - 2 dot = (acc-1536)/128 + an
                float dist = fmaxf(fmaf(bv - 1536.0f, 0.0078125f, anr), 0.f);
                dsum += (double)dist;
            }
        } else if (lc == 0) {
            u32 idx = atomicAdd(flagcnt, 1u);
            flaglist[idx] = (u32)grow;
        }
    }
    dsum += __shfl_xor(dsum, 32);
    if (lane == 0) atomicAdd(loss_sum, dsum);
}

// ---------- rescan: block-per-flagged-row, exact fp32 argmin (R1 chains)
#define RS_GRID 4096
__launch_bounds__(256)
__global__ void vq_rescan(const float* __restrict__ x,
                          const float* __restrict__ emb,
                          const float* __restrict__ bn,
                          const u32* __restrict__ flagcnt,
                          const u32* __restrict__ flaglist,
                          float* __restrict__ out,
                          int* __restrict__ counts,
                          double* __restrict__ loss_sum) {
    __shared__ float Xs[DIM];
    __shared__ u64 wred[4];
    const u32 n = *flagcnt;
    const int t = threadIdx.x;

    for (u32 i = blockIdx.x; i < n; i += RS_GRID) {
        const int row = (int)flaglist[i];
        if (t < DIM) Xs[t] = x[(size_t)row * DIM + t];
        __syncthreads();

        float an = 0.f;
#pragma unroll
        for (int d = 0; d < DIM; ++d) an = fmaf(Xs[d], Xs[d], an);

        u64 bestp = ~0ull;
#pragma unroll
        for (int cc = 0; cc < 4; ++cc) {
            const int k = cc * 256 + t;
            const float* ek = emb + (size_t)k * DIM;
            float q0 = 0.f, q1 = 0.f, q2 = 0.f, q3 = 0.f;
#pragma unroll
            for (int d = 0; d < DIM; d += 4) {
                float4 ev = *(const float4*)(ek + d);
                q0 = fmaf(Xs[d],     ev.x, q0);
                q1 = fmaf(Xs[d + 1], ev.y, q1);
                q2 = fmaf(Xs[d + 2], ev.z, q2);
                q3 = fmaf(Xs[d + 3], ev.w, q3);
            }
            float dot = (q0 + q1) + (q2 + q3);
            float dist = fmaxf((an + bn[k]) - 2.0f * dot, 0.f);
            u64 p = ((u64)__float_as_uint(dist) << 32) | (u32)k;
            if (p < bestp) bestp = p;
        }
#pragma unroll
        for (int m = 1; m < 64; m <<= 1) {
            u64 o = __shfl_xor(bestp, m);
            if (o < bestp) bestp = o;
        }
        if ((t & 63) == 0) wred[t >> 6] = bestp;
        __syncthreads();
        u64 b = wred[0];
        if (wred[1] < b) b = wred[1];
        if (wred[2] < b) b = wred[2];
        if (wred[3] < b) b = wred[3];
        const int bk = (int)(u32)b;

        if (t < DIM) {
            float qv = emb[(size_t)bk * DIM + t];
            out[(size_t)row * DIM + t] = qv;
            float dx = qv - Xs[t];
            double ds = (double)(dx * dx);
#pragma unroll
            for (int m = 1; m < 64; m <<= 1) ds += __shfl_xor(ds, m);
            if (t == 0) {
                atomicAdd(loss_sum, ds);
                atomicAdd(&counts[bk], 1);
            }
        }
        __syncthreads();
    }
}

__global__ void vq_final_kernel(const int* __restrict__ counts,
                                const double* __restrict__ loss_sum,
                                float* __restrict__ out) {
    __shared__ double red[16];
    const int t = threadIdx.x;           // 1024 threads
    float p = (float)counts[t] / (float)N_ROWS;
    double term = (double)p * log((double)p + 1e-10);
#pragma unroll
    for (int off = 32; off > 0; off >>= 1) term += __shfl_down(term, off);
    if ((t & 63) == 0) red[t >> 6] = term;
    __syncthreads();
    if (t == 0) {
        double s = 0.0;
#pragma unroll
        for (int w = 0; w < 16; ++w) s += red[w];
        const size_t base = (size_t)N_ROWS * DIM;
        out[base]     = (float)(1.5 * (*loss_sum) / (double)((size_t)N_ROWS * DIM));
        out[base + 1] = (float)exp(-s);
    }
}

extern "C" void kernel_launch(void* const* d_in, const int* in_sizes, int n_in,
                              void* d_out, int out_size, void* d_ws, size_t ws_size,
                              hipStream_t stream) {
    const float* x   = (const float*)d_in[0];
    const float* emb = (const float*)d_in[1];
    float* out = (float*)d_out;

    char* ws = (char*)d_ws;
    double* loss_sum = (double*)ws;
    u32*  flagcnt  = (u32*)(ws + WS_FLAGCNT_OFF);
    int*  counts   = (int*)(ws + WS_COUNTS_OFF);
    float* bn      = (float*)(ws + WS_BN_OFF);
    float* nbs     = (float*)(ws + WS_NBS_OFF);
    char* Bc       = ws + WS_BC_OFF;
    u32*  flist    = (u32*)(ws + WS_FLIST_OFF);

    hipMemsetAsync(d_ws, 0, WS_ZERO_BYTES, stream);

    vq_prep<<<KCODES / 256, 256, 0, stream>>>(emb, bn, nbs, Bc);
    vq_screen<<<N_ROWS / 128, 256, 0, stream>>>(x, Bc, nbs, emb, out,
                                                counts, loss_sum, flagcnt, flist);
    vq_rescan<<<RS_GRID, 256, 0, stream>>>(x, emb, bn, flagcnt, flist,
                                           out, counts, loss_sum);
    vq_final_kernel<<<1, 1024, 0, stream>>>(counts, loss_sum, out);
}